// Round 6
// baseline (83.912 us; speedup 1.0000x reference)
//
#include <hip/hip_runtime.h>
#include <hip/hip_bf16.h>

#define B_ 4
#define Q_ 256
#define K_ 1024
#define D_ 256
#define LOG2E 1.44269504f

__device__ __forceinline__ float fexp2(float x) {
    float r; asm("v_exp_f32 %0, %1" : "=v"(r) : "v"(x)); return r;
}
__device__ __forceinline__ float frcp(float x) {
    float r; asm("v_rcp_f32 %0, %1" : "=v"(r) : "v"(x)); return r;
}

// Fused: blocks (x<80, y) do the two projections; blocks (80, y) do per-batch
// mask compaction (batch = y).
__global__ __launch_bounds__(256) void prep_kernel(const float* __restrict__ q,
                                                   const float* __restrict__ k,
                                                   const float* __restrict__ Wq,
                                                   const float* __restrict__ Wk,
                                                   const int* __restrict__ mask,
                                                   float* __restrict__ qp,
                                                   float* __restrict__ kp,
                                                   ushort* __restrict__ kidx,
                                                   int* __restrict__ nvalid,
                                                   float scale) {
    const int t = threadIdx.x;
    if (blockIdx.x >= 80) {
        if (t >= 64) return;
        const int b = blockIdx.y, lane = t;
        const int* m = mask + b * K_;
        const int base = lane * 16;
        int cnt = 0;
#pragma unroll
        for (int i = 0; i < 16; ++i) cnt += (m[base + i] != 0);
        int inc = cnt;
#pragma unroll
        for (int d = 1; d < 64; d <<= 1) {
            int tt = __shfl_up(inc, d);
            if (lane >= d) inc += tt;
        }
        const int total = __shfl(inc, 63);
        int pos = inc - cnt;
        ushort* kb = kidx + b * K_;
        for (int i = 0; i < 16; ++i) {
            int kk = base + i;
            if (m[kk] != 0) kb[pos++] = (ushort)kk;
        }
        for (int j = total + lane; j < K_; j += 64) kb[j] = 0;
        if (lane == 0) nvalid[b] = total;
        return;
    }
    const float* A; const float* W; float* outp; int m0;
    if (blockIdx.x < 16) { A = q; W = Wq; outp = qp; m0 = blockIdx.x * 64; }
    else                 { A = k; W = Wk; outp = kp; m0 = (blockIdx.x - 16) * 64; }
    __shared__ float As[16][65];
    __shared__ float Ws[16][64];
    const int tx = t & 15, ty = t >> 4;
    const int n0 = blockIdx.y * 64;
    const int ar = t >> 2, ac = (t & 3) * 4;
    const int wr = t >> 4, wc = (t & 15) * 4;
    float c[4][4] = {};
    for (int kb = 0; kb < 256; kb += 16) {
        __syncthreads();
        float4 av = *(const float4*)(A + (size_t)(m0 + ar) * 256 + kb + ac);
        As[ac + 0][ar] = av.x; As[ac + 1][ar] = av.y;
        As[ac + 2][ar] = av.z; As[ac + 3][ar] = av.w;
        float4 wvv = *(const float4*)(W + (size_t)(kb + wr) * 256 + n0 + wc);
        wvv.x *= scale; wvv.y *= scale; wvv.z *= scale; wvv.w *= scale;
        *(float4*)(&Ws[wr][wc]) = wvv;
        __syncthreads();
#pragma unroll
        for (int kk = 0; kk < 16; ++kk) {
            float4 bv = *(const float4*)(&Ws[kk][tx * 4]);
#pragma unroll
            for (int i = 0; i < 4; ++i) {
                float a = As[kk][ty * 4 + i];
                c[i][0] = fmaf(a, bv.x, c[i][0]);
                c[i][1] = fmaf(a, bv.y, c[i][1]);
                c[i][2] = fmaf(a, bv.z, c[i][2]);
                c[i][3] = fmaf(a, bv.w, c[i][3]);
            }
        }
    }
#pragma unroll
    for (int i = 0; i < 4; ++i) {
        float4 o = make_float4(c[i][0], c[i][1], c[i][2], c[i][3]);
        *(float4*)(outp + (size_t)(m0 + ty * 4 + i) * 256 + n0 + tx * 4) = o;
    }
}

// Grid = 1024 = B * 128 qpairs * 2 k-halves. 512 threads = 8 waves.
// lane = (kl = lane&31 : k in tile, eh = lane>>5 : e-half). Wave w owns
// e-chunk [w*32, w*32+32); each lane handles 16 e's for 32 k's.
// __launch_bounds__(512,2): hipcc treats arg2 as workgroups/CU (measured:
// (512,4)->VGPR 64, (512,6)->VGPR 40); 2 -> cap 128 VGPR -> NO SPILLS.
__global__ __launch_bounds__(512, 2) void attn_kernel(const float* __restrict__ qp,
                                                      const float* __restrict__ kp,
                                                      const float* __restrict__ v,
                                                      const ushort* __restrict__ kidx_g,
                                                      const int* __restrict__ nvalid_g,
                                                      const float* __restrict__ wv,
                                                      float* __restrict__ O_part,
                                                      float* __restrict__ ml_part) {
    __shared__ union {
        float4 kp4[32 * 65];            // 33,280 B : kp tile, row stride 65 f4
        float4 pv[8 * 2 * 64];          // 16,384 B : PV partials (phase 2)
    } u;
    __shared__ float  s_red[8 * 66];    //  2,112 B : cross-wave partials (padded)
    __shared__ float  s_sc[2][512];     //  4,096 B : scores then probs
    __shared__ ushort s_kidx[512];      //  1,024 B : compacted k indices

    const int tid  = threadIdx.x;
    const int lane = tid & 63;
    const int wave = tid >> 6;
    const int kl   = lane & 31;
    const int eh   = lane >> 5;

    int bid = blockIdx.x;
    bid = (bid & 7) * 128 + (bid >> 3);          // bijective XCD swizzle
    const int b  = bid >> 8;
    const int qi = (bid >> 1) & 127;
    const int h  = bid & 1;
    const int q0 = qi * 2;
    const int part = (b * 128 + qi) * 2 + h;

    const int nvs   = nvalid_g[b];
    const int half  = (nvs + 1) >> 1;
    const int kbase = h ? half : 0;
    const int range = h ? (nvs - half) : half;
    const int ntiles = (range + 31) >> 5;
    const int ntot   = ntiles << 5;

    if (tid < 512) {
        int j = tid;
        s_kidx[j] = (j < range) ? kidx_g[b * K_ + kbase + j] : (ushort)0;
    }

    // per-lane registers: 16 e's of this wave's chunk
    float qp_r[2][16], wv_r[16];
    {
        const int e0 = wave * 32 + eh * 16;
#pragma unroll
        for (int qq = 0; qq < 2; ++qq) {
            const float4* p = (const float4*)(qp + ((size_t)(b * Q_ + q0 + qq) << 8) + e0);
#pragma unroll
            for (int i = 0; i < 4; ++i) {
                float4 x = p[i];
                qp_r[qq][i * 4 + 0] = x.x; qp_r[qq][i * 4 + 1] = x.y;
                qp_r[qq][i * 4 + 2] = x.z; qp_r[qq][i * 4 + 3] = x.w;
            }
        }
        const float4* pw = (const float4*)(wv + e0);
#pragma unroll
        for (int i = 0; i < 4; ++i) {
            float4 x = pw[i];
            wv_r[i * 4 + 0] = x.x; wv_r[i * 4 + 1] = x.y;
            wv_r[i * 4 + 2] = x.z; wv_r[i * 4 + 3] = x.w;
        }
    }
    __syncthreads();   // s_kidx ready

    const float4* srcb = (const float4*)(kp + ((size_t)b * K_ << 8));
    // staging: thread loads rows (wave + i*8), col = lane  (row idx wave-uniform)
    float4 pfA0 = {0,0,0,0}, pfA1 = {0,0,0,0}, pfA2 = {0,0,0,0}, pfA3 = {0,0,0,0};
    float4 pfB0 = {0,0,0,0}, pfB1 = {0,0,0,0}, pfB2 = {0,0,0,0}, pfB3 = {0,0,0,0};
    if (ntiles > 0) {
        pfA0 = srcb[((size_t)s_kidx[wave +  0] << 6) + lane];
        pfA1 = srcb[((size_t)s_kidx[wave +  8] << 6) + lane];
        pfA2 = srcb[((size_t)s_kidx[wave + 16] << 6) + lane];
        pfA3 = srcb[((size_t)s_kidx[wave + 24] << 6) + lane];
    }

    for (int kt = 0; kt < ntiles; ++kt) {
        // ---- reduce previous tile's partials (s_red stable since last barrier) ----
        if (kt > 0) {
            const int w = tid & 7, p = tid >> 3;
            float s = s_red[w * 66 + p];
            s += __shfl_xor(s, 1);
            s += __shfl_xor(s, 2);
            s += __shfl_xor(s, 4);
            if (w == 0) {
                const int idx = (kt - 1) * 32 + (p & 31);
                s_sc[p >> 5][idx] = (idx < range) ? (-2.0f * s) : -3.0e38f;
            }
        }
        // ---- commit staged tile to LDS (vmcnt wait folded here) ----
        u.kp4[(wave +  0) * 65 + lane] = pfA0;
        u.kp4[(wave +  8) * 65 + lane] = pfA1;
        u.kp4[(wave + 16) * 65 + lane] = pfA2;
        u.kp4[(wave + 24) * 65 + lane] = pfA3;
        __syncthreads();   // kp4 ready; s_sc[kt-1] done

        // ---- prefetch next tile (latency hides under compute) ----
        if (kt + 1 < ntiles) {
            const int o = (kt + 1) * 32;
            pfB0 = srcb[((size_t)s_kidx[o + wave +  0] << 6) + lane];
            pfB1 = srcb[((size_t)s_kidx[o + wave +  8] << 6) + lane];
            pfB2 = srcb[((size_t)s_kidx[o + wave + 16] << 6) + lane];
            pfB3 = srcb[((size_t)s_kidx[o + wave + 24] << 6) + lane];
        }

        // ---- sigmoid-weighted partial scores ----
        float a0 = 0.f, a1 = 0.f;
        const float4* krow = u.kp4 + kl * 65 + wave * 8 + eh * 4;
#pragma unroll
        for (int t4 = 0; t4 < 4; ++t4) {
            float4 kv = krow[t4];
            float kc[4] = {kv.x, kv.y, kv.z, kv.w};
#pragma unroll
            for (int j = 0; j < 4; ++j) {
                const int e = t4 * 4 + j;
                const float w = wv_r[e];
                float r0 = frcp(fexp2(qp_r[0][e] + kc[j]) + 1.0f);
                a0 = fmaf(w, r0, a0);
                float r1 = frcp(fexp2(qp_r[1][e] + kc[j]) + 1.0f);
                a1 = fmaf(w, r1, a1);
            }
        }
        a0 += __shfl_xor(a0, 32);
        a1 += __shfl_xor(a1, 32);
        if (eh == 0) {
            s_red[wave * 66 + kl]      = a0;
            s_red[wave * 66 + 32 + kl] = a1;
        }
        __syncthreads();   // s_red ready; all kp4 reads done

        pfA0 = pfB0; pfA1 = pfB1; pfA2 = pfB2; pfA3 = pfB3;
    }

    // ---- final tile's reduce ----
    if (ntiles > 0) {
        const int w = tid & 7, p = tid >> 3;
        float s = s_red[w * 66 + p];
        s += __shfl_xor(s, 1);
        s += __shfl_xor(s, 2);
        s += __shfl_xor(s, 4);
        if (w == 0) {
            const int idx = (ntiles - 1) * 32 + (p & 31);
            s_sc[p >> 5][idx] = (idx < range) ? (-2.0f * s) : -3.0e38f;
        }
    }
    __syncthreads();

    // ---- local (unnormalized) softmax: wave qq < 2 handles q = qq ----
    if (wave < 2) {
        const int qq = wave;
        float mx = -3.0e38f;
        for (int j = lane; j < ntot; j += 64) mx = fmaxf(mx, s_sc[qq][j]);
#pragma unroll
        for (int off = 32; off > 0; off >>= 1) mx = fmaxf(mx, __shfl_xor(mx, off));
        float sum = 0.f;
        for (int j = lane; j < ntot; j += 64) {
            float e = fexp2((s_sc[qq][j] - mx) * LOG2E);
            s_sc[qq][j] = e;
            sum += e;
        }
#pragma unroll
        for (int off = 32; off > 0; off >>= 1) sum += __shfl_xor(sum, off);
        if (lane == 0) {
            ml_part[part * 4 + qq * 2 + 0] = mx;
            ml_part[part * 4 + qq * 2 + 1] = sum;
        }
    }
    __syncthreads();

    // ---- PV (unnormalized): thread -> (d-float4 = tid&63, k-chunk = tid>>6) ----
    {
        const int dl = tid & 63;
        const int kq = tid >> 6;
        const int chunk = ntiles * 4;
        float4 o0 = {0, 0, 0, 0}, o1 = {0, 0, 0, 0};
        const float4* v4 = (const float4*)(v + ((size_t)b * K_ << 8));
        for (int k = kq * chunk; k < kq * chunk + chunk; ++k) {
            int vr = s_kidx[k];
            float4 vv = v4[((size_t)vr << 6) + dl];
            float p0 = s_sc[0][k], p1 = s_sc[1][k];
            o0.x = fmaf(p0, vv.x, o0.x); o0.y = fmaf(p0, vv.y, o0.y);
            o0.z = fmaf(p0, vv.z, o0.z); o0.w = fmaf(p0, vv.w, o0.w);
            o1.x = fmaf(p1, vv.x, o1.x); o1.y = fmaf(p1, vv.y, o1.y);
            o1.z = fmaf(p1, vv.z, o1.z); o1.w = fmaf(p1, vv.w, o1.w);
        }
        u.pv[(kq * 2 + 0) * 64 + dl] = o0;
        u.pv[(kq * 2 + 1) * 64 + dl] = o1;
        __syncthreads();
        if (tid < 128) {
            const int qq = tid >> 6, c = tid & 63;
            float4 s = {0, 0, 0, 0};
#pragma unroll
            for (int g = 0; g < 8; ++g) {
                float4 x = u.pv[(g * 2 + qq) * 64 + c];
                s.x += x.x; s.y += x.y; s.z += x.z; s.w += x.w;
            }
            ((float4*)O_part)[((size_t)part * 2 + qq) * 64 + c] = s;
        }
    }
}

// Merge the two k-halves.
__global__ __launch_bounds__(128) void combine_kernel(const float* __restrict__ O_part,
                                                      const float* __restrict__ ml,
                                                      float* __restrict__ out) {
    const int bid = blockIdx.x;              // 512 = B * 128 qpairs
    const int b = bid >> 7, qi = bid & 127;
    const int p0 = (b * 128 + qi) * 2;
    const int t = threadIdx.x;
    const int qq = t >> 6, c = t & 63;
    float m0 = ml[p0 * 4 + qq * 2], l0 = ml[p0 * 4 + qq * 2 + 1];
    float m1 = ml[(p0 + 1) * 4 + qq * 2], l1 = ml[(p0 + 1) * 4 + qq * 2 + 1];
    float m = fmaxf(m0, m1);
    float s0 = fexp2((m0 - m) * LOG2E);
    float s1 = fexp2((m1 - m) * LOG2E);
    float inv = frcp(l0 * s0 + l1 * s1);
    const float4* O0 = (const float4*)O_part + ((size_t)p0 * 2 + qq) * 64;
    const float4* O1 = (const float4*)O_part + ((size_t)(p0 + 1) * 2 + qq) * 64;
    float4 a = O0[c], bb = O1[c];
    float4 r;
    r.x = (a.x * s0 + bb.x * s1) * inv;
    r.y = (a.y * s0 + bb.y * s1) * inv;
    r.z = (a.z * s0 + bb.z * s1) * inv;
    r.w = (a.w * s0 + bb.w * s1) * inv;
    ((float4*)out)[((size_t)(b * Q_ + qi * 2 + qq) << 6) + c] = r;
}

extern "C" void kernel_launch(void* const* d_in, const int* in_sizes, int n_in,
                              void* d_out, int out_size, void* d_ws, size_t ws_size,
                              hipStream_t stream) {
    const float* q    = (const float*)d_in[0];
    const float* k    = (const float*)d_in[1];
    const float* v    = (const float*)d_in[2];
    const int*   mask = (const int*)d_in[3];
    const float* Wq   = (const float*)d_in[4];
    const float* Wk   = (const float*)d_in[5];
    const float* wv   = (const float*)d_in[6];
    float* out = (float*)d_out;

    float* qp     = (float*)d_ws;                        // 1 MB
    float* kp     = qp + (size_t)B_ * Q_ * D_;           // 4 MB
    float* O_part = kp + (size_t)B_ * K_ * D_;           // 2 MB
    float* ml     = O_part + (size_t)1024 * 2 * D_;      // 16 KB
    ushort* kidx  = (ushort*)(ml + 4096);                // 8 KB
    int* nvalid   = (int*)(kidx + (size_t)B_ * K_);      // 16 B

    const float c2 = 2.885390082f;  // 2*log2(e)

    prep_kernel<<<dim3(81, 4), 256, 0, stream>>>(q, k, Wq, Wk, mask, qp, kp, kidx, nvalid, c2);
    attn_kernel<<<dim3(1024), 512, 0, stream>>>(qp, kp, v, kidx, nvalid, wv, O_part, ml);
    combine_kernel<<<dim3(512), 128, 0, stream>>>(O_part, ml, out);
}

// Round 7
// 76.578 us; speedup vs baseline: 1.0958x; 1.0958x over previous
//
#include <hip/hip_runtime.h>
#include <hip/hip_bf16.h>

#define B_ 4
#define Q_ 256
#define K_ 1024
#define D_ 256
#define LOG2E 1.44269504f

__device__ __forceinline__ float fexp2(float x) {
    float r; asm("v_exp_f32 %0, %1" : "=v"(r) : "v"(x)); return r;
}
__device__ __forceinline__ float frcp(float x) {
    float r; asm("v_rcp_f32 %0, %1" : "=v"(r) : "v"(x)); return r;
}
__device__ __forceinline__ void gload_lds16(const void* g, void* l) {
    __builtin_amdgcn_global_load_lds((const __attribute__((address_space(1))) void*)g,
                                     (__attribute__((address_space(3))) void*)l, 16, 0, 0);
}

// Fused: blocks (x<80, y) do the two projections (output = exp2(c2 * A@W));
// blocks (80, y) do per-batch mask compaction.
__global__ __launch_bounds__(256) void prep_kernel(const float* __restrict__ q,
                                                   const float* __restrict__ k,
                                                   const float* __restrict__ Wq,
                                                   const float* __restrict__ Wk,
                                                   const int* __restrict__ mask,
                                                   float* __restrict__ qpE,
                                                   float* __restrict__ kpE,
                                                   ushort* __restrict__ kidx,
                                                   int* __restrict__ nvalid,
                                                   float scale) {
    const int t = threadIdx.x;
    if (blockIdx.x >= 80) {
        if (t >= 64) return;
        const int b = blockIdx.y, lane = t;
        const int* m = mask + b * K_;
        const int base = lane * 16;
        int cnt = 0;
#pragma unroll
        for (int i = 0; i < 16; ++i) cnt += (m[base + i] != 0);
        int inc = cnt;
#pragma unroll
        for (int d = 1; d < 64; d <<= 1) {
            int tt = __shfl_up(inc, d);
            if (lane >= d) inc += tt;
        }
        const int total = __shfl(inc, 63);
        int pos = inc - cnt;
        ushort* kb = kidx + b * K_;
        for (int i = 0; i < 16; ++i) {
            int kk = base + i;
            if (m[kk] != 0) kb[pos++] = (ushort)kk;
        }
        for (int j = total + lane; j < K_; j += 64) kb[j] = 0;
        if (lane == 0) nvalid[b] = total;
        return;
    }
    const float* A; const float* W; float* outp; int m0;
    if (blockIdx.x < 16) { A = q; W = Wq; outp = qpE; m0 = blockIdx.x * 64; }
    else                 { A = k; W = Wk; outp = kpE; m0 = (blockIdx.x - 16) * 64; }
    __shared__ float As[16][65];
    __shared__ float Ws[16][64];
    const int tx = t & 15, ty = t >> 4;
    const int n0 = blockIdx.y * 64;
    const int ar = t >> 2, ac = (t & 3) * 4;
    const int wr = t >> 4, wc = (t & 15) * 4;
    float c[4][4] = {};
    for (int kb = 0; kb < 256; kb += 16) {
        __syncthreads();
        float4 av = *(const float4*)(A + (size_t)(m0 + ar) * 256 + kb + ac);
        As[ac + 0][ar] = av.x; As[ac + 1][ar] = av.y;
        As[ac + 2][ar] = av.z; As[ac + 3][ar] = av.w;
        float4 wvv = *(const float4*)(W + (size_t)(kb + wr) * 256 + n0 + wc);
        wvv.x *= scale; wvv.y *= scale; wvv.z *= scale; wvv.w *= scale;
        *(float4*)(&Ws[wr][wc]) = wvv;
        __syncthreads();
#pragma unroll
        for (int kk = 0; kk < 16; ++kk) {
            float4 bv = *(const float4*)(&Ws[kk][tx * 4]);
#pragma unroll
            for (int i = 0; i < 4; ++i) {
                float a = As[kk][ty * 4 + i];
                c[i][0] = fmaf(a, bv.x, c[i][0]);
                c[i][1] = fmaf(a, bv.y, c[i][1]);
                c[i][2] = fmaf(a, bv.z, c[i][2]);
                c[i][3] = fmaf(a, bv.w, c[i][3]);
            }
        }
    }
    // epilogue: write exp2 of the scaled projection (hoists exp out of attn)
#pragma unroll
    for (int i = 0; i < 4; ++i) {
        float4 o = make_float4(fexp2(c[i][0]), fexp2(c[i][1]),
                               fexp2(c[i][2]), fexp2(c[i][3]));
        *(float4*)(outp + (size_t)(m0 + ty * 4 + i) * 256 + n0 + tx * 4) = o;
    }
}

// Grid = 1024 = B * 128 qpairs * 2 k-halves. 512 threads = 8 waves.
// A=exp2(c*qp) in regs, B=exp2(c*kp) staged via global_load_lds dbuf.
// sigmoid(2(qp+kp)) = 1/(A*B+1): inner loop = fma, rcp, fma.
__global__ __launch_bounds__(512, 2) void attn_kernel(const float* __restrict__ qpE,
                                                      const float* __restrict__ kpE,
                                                      const float* __restrict__ v,
                                                      const ushort* __restrict__ kidx_g,
                                                      const int* __restrict__ nvalid_g,
                                                      const float* __restrict__ wv,
                                                      float* __restrict__ O_part,
                                                      float* __restrict__ ml_part) {
    __shared__ float4 s_kp[2][32 * 65];   // 66,560 B : dbuf kp-exp tiles (row stride 65 f4)
    __shared__ float  s_red[8 * 66];      //  2,112 B : cross-wave partials
    __shared__ float  s_sc[2][512];       //  4,096 B : scores then probs
    __shared__ ushort s_kidx[512];        //  1,024 B : compacted k indices

    const int tid  = threadIdx.x;
    const int lane = tid & 63;
    const int wave = tid >> 6;
    const int kl   = lane & 31;
    const int eh   = lane >> 5;

    int bid = blockIdx.x;
    bid = (bid & 7) * 128 + (bid >> 3);          // bijective XCD swizzle
    const int b  = bid >> 8;
    const int qi = (bid >> 1) & 127;
    const int h  = bid & 1;
    const int q0 = qi * 2;
    const int part = (b * 128 + qi) * 2 + h;

    const int nvs   = nvalid_g[b];
    const int half  = (nvs + 1) >> 1;
    const int kbase = h ? half : 0;
    const int range = h ? (nvs - half) : half;
    const int ntiles = (range + 31) >> 5;
    const int ntot   = ntiles << 5;

    s_kidx[tid] = (tid < range) ? kidx_g[b * K_ + kbase + tid] : (ushort)0;

    // per-lane registers: A = exp2(c*qp) for 16 e's, plus wv chunk
    float qp_A[2][16], wv_r[16];
    {
        const int e0 = wave * 32 + eh * 16;
#pragma unroll
        for (int qq = 0; qq < 2; ++qq) {
            const float4* p = (const float4*)(qpE + ((size_t)(b * Q_ + q0 + qq) << 8) + e0);
#pragma unroll
            for (int i = 0; i < 4; ++i) {
                float4 x = p[i];
                qp_A[qq][i * 4 + 0] = x.x; qp_A[qq][i * 4 + 1] = x.y;
                qp_A[qq][i * 4 + 2] = x.z; qp_A[qq][i * 4 + 3] = x.w;
            }
        }
        const float4* pw = (const float4*)(wv + e0);
#pragma unroll
        for (int i = 0; i < 4; ++i) {
            float4 x = pw[i];
            wv_r[i * 4 + 0] = x.x; wv_r[i * 4 + 1] = x.y;
            wv_r[i * 4 + 2] = x.z; wv_r[i * 4 + 3] = x.w;
        }
    }
    __syncthreads();   // s_kidx ready

    const float4* srcb = (const float4*)(kpE + ((size_t)b * K_ << 8));

    // prologue: stage tile 0 into buf 0 (4 rows per wave, 1 instr per row)
    if (ntiles > 0) {
#pragma unroll
        for (int i = 0; i < 4; ++i) {
            const int row = wave + i * 8;
            const int gr = s_kidx[row];
            gload_lds16(srcb + ((size_t)gr << 6) + lane, &s_kp[0][row * 65]);
        }
    }

    for (int kt = 0; kt < ntiles; ++kt) {
        const int bf = kt & 1;
        // ---- (B) reduce previous tile's partials (s_red stable since last barrier) ----
        if (kt > 0) {
            const int w = tid & 7, p = tid >> 3;
            float s = s_red[w * 66 + p];
            s += __shfl_xor(s, 1);
            s += __shfl_xor(s, 2);
            s += __shfl_xor(s, 4);
            if (w == 0) {
                const int idx = (kt - 1) * 32 + (p & 31);
                s_sc[p >> 5][idx] = (idx < range) ? (-2.0f * s) : -3.0e38f;
            }
        }
        __syncthreads();   // bar1: tile kt loads drained; s_red read/write separated

        // ---- (A) issue next tile's loads (hide under compute below) ----
        if (kt + 1 < ntiles) {
            const int o = (kt + 1) * 32;
#pragma unroll
            for (int i = 0; i < 4; ++i) {
                const int row = wave + i * 8;
                const int gr = s_kidx[o + row];
                gload_lds16(srcb + ((size_t)gr << 6) + lane, &s_kp[bf ^ 1][row * 65]);
            }
        }

        // ---- (C) sigmoid-weighted partial scores: fma, rcp, fma ----
        float a0 = 0.f, a1 = 0.f;
        const float4* krow = s_kp[bf] + kl * 65 + wave * 8 + eh * 4;
#pragma unroll
        for (int t4 = 0; t4 < 4; ++t4) {
            float4 kv = krow[t4];
            float kc[4] = {kv.x, kv.y, kv.z, kv.w};
#pragma unroll
            for (int j = 0; j < 4; ++j) {
                const int e = t4 * 4 + j;
                const float w = wv_r[e];
                float r0 = frcp(fmaf(qp_A[0][e], kc[j], 1.0f));
                a0 = fmaf(w, r0, a0);
                float r1 = frcp(fmaf(qp_A[1][e], kc[j], 1.0f));
                a1 = fmaf(w, r1, a1);
            }
        }
        a0 += __shfl_xor(a0, 32);
        a1 += __shfl_xor(a1, 32);
        if (eh == 0) {
            s_red[wave * 66 + kl]      = a0;
            s_red[wave * 66 + 32 + kl] = a1;
        }
        __syncthreads();   // bar2: s_red ready; kt+1 loads complete; kp reads retired
    }

    // ---- final tile's reduce ----
    if (ntiles > 0) {
        const int w = tid & 7, p = tid >> 3;
        float s = s_red[w * 66 + p];
        s += __shfl_xor(s, 1);
        s += __shfl_xor(s, 2);
        s += __shfl_xor(s, 4);
        if (w == 0) {
            const int idx = (ntiles - 1) * 32 + (p & 31);
            s_sc[p >> 5][idx] = (idx < range) ? (-2.0f * s) : -3.0e38f;
        }
    }
    __syncthreads();

    // ---- local (unnormalized) softmax: wave qq < 2 handles q = qq ----
    if (wave < 2) {
        const int qq = wave;
        float mx = -3.0e38f;
        for (int j = lane; j < ntot; j += 64) mx = fmaxf(mx, s_sc[qq][j]);
#pragma unroll
        for (int off = 32; off > 0; off >>= 1) mx = fmaxf(mx, __shfl_xor(mx, off));
        float sum = 0.f;
        for (int j = lane; j < ntot; j += 64) {
            float e = fexp2((s_sc[qq][j] - mx) * LOG2E);
            s_sc[qq][j] = e;
            sum += e;
        }
#pragma unroll
        for (int off = 32; off > 0; off >>= 1) sum += __shfl_xor(sum, off);
        if (lane == 0) {
            ml_part[part * 4 + qq * 2 + 0] = mx;
            ml_part[part * 4 + qq * 2 + 1] = sum;
        }
    }
    __syncthreads();

    // ---- PV (unnormalized): thread -> (d-float4 = tid&63, k-chunk = tid>>6) ----
    {
        const int dl = tid & 63;
        const int kq = tid >> 6;
        const int chunk = ntiles * 4;
        float4 o0 = {0, 0, 0, 0}, o1 = {0, 0, 0, 0};
        const float4* v4 = (const float4*)(v + ((size_t)b * K_ << 8));
        for (int k = kq * chunk; k < kq * chunk + chunk; ++k) {
            int vr = s_kidx[k];
            float4 vv = v4[((size_t)vr << 6) + dl];
            float p0 = s_sc[0][k], p1 = s_sc[1][k];
            o0.x = fmaf(p0, vv.x, o0.x); o0.y = fmaf(p0, vv.y, o0.y);
            o0.z = fmaf(p0, vv.z, o0.z); o0.w = fmaf(p0, vv.w, o0.w);
            o1.x = fmaf(p1, vv.x, o1.x); o1.y = fmaf(p1, vv.y, o1.y);
            o1.z = fmaf(p1, vv.z, o1.z); o1.w = fmaf(p1, vv.w, o1.w);
        }
        float4* s_pv = s_kp[0];
        s_pv[(kq * 2 + 0) * 64 + dl] = o0;
        s_pv[(kq * 2 + 1) * 64 + dl] = o1;
        __syncthreads();
        if (tid < 128) {
            const int qq = tid >> 6, c = tid & 63;
            float4 s = {0, 0, 0, 0};
#pragma unroll
            for (int g = 0; g < 8; ++g) {
                float4 x = s_pv[(g * 2 + qq) * 64 + c];
                s.x += x.x; s.y += x.y; s.z += x.z; s.w += x.w;
            }
            ((float4*)O_part)[((size_t)part * 2 + qq) * 64 + c] = s;
        }
    }
}

// Merge the two k-halves.
__global__ __launch_bounds__(128) void combine_kernel(const float* __restrict__ O_part,
                                                      const float* __restrict__ ml,
                                                      float* __restrict__ out) {
    const int bid = blockIdx.x;              // 512 = B * 128 qpairs
    const int b = bid >> 7, qi = bid & 127;
    const int p0 = (b * 128 + qi) * 2;
    const int t = threadIdx.x;
    const int qq = t >> 6, c = t & 63;
    float m0 = ml[p0 * 4 + qq * 2], l0 = ml[p0 * 4 + qq * 2 + 1];
    float m1 = ml[(p0 + 1) * 4 + qq * 2], l1 = ml[(p0 + 1) * 4 + qq * 2 + 1];
    float m = fmaxf(m0, m1);
    float s0 = fexp2((m0 - m) * LOG2E);
    float s1 = fexp2((m1 - m) * LOG2E);
    float inv = frcp(l0 * s0 + l1 * s1);
    const float4* O0 = (const float4*)O_part + ((size_t)p0 * 2 + qq) * 64;
    const float4* O1 = (const float4*)O_part + ((size_t)(p0 + 1) * 2 + qq) * 64;
    float4 a = O0[c], bb = O1[c];
    float4 r;
    r.x = (a.x * s0 + bb.x * s1) * inv;
    r.y = (a.y * s0 + bb.y * s1) * inv;
    r.z = (a.z * s0 + bb.z * s1) * inv;
    r.w = (a.w * s0 + bb.w * s1) * inv;
    ((float4*)out)[((size_t)(b * Q_ + qi * 2 + qq) << 6) + c] = r;
}

extern "C" void kernel_launch(void* const* d_in, const int* in_sizes, int n_in,
                              void* d_out, int out_size, void* d_ws, size_t ws_size,
                              hipStream_t stream) {
    const float* q    = (const float*)d_in[0];
    const float* k    = (const float*)d_in[1];
    const float* v    = (const float*)d_in[2];
    const int*   mask = (const int*)d_in[3];
    const float* Wq   = (const float*)d_in[4];
    const float* Wk   = (const float*)d_in[5];
    const float* wv   = (const float*)d_in[6];
    float* out = (float*)d_out;

    float* qpE    = (float*)d_ws;                        // 1 MB  (exp2 of c2*qp)
    float* kpE    = qpE + (size_t)B_ * Q_ * D_;          // 4 MB  (exp2 of c2*kp)
    float* O_part = kpE + (size_t)B_ * K_ * D_;          // 2 MB
    float* ml     = O_part + (size_t)1024 * 2 * D_;      // 16 KB
    ushort* kidx  = (ushort*)(ml + 4096);                // 8 KB
    int* nvalid   = (int*)(kidx + (size_t)B_ * K_);      // 16 B

    const float c2 = 2.885390082f;  // 2*log2(e)

    prep_kernel<<<dim3(81, 4), 256, 0, stream>>>(q, k, Wq, Wk, mask, qpE, kpE, kidx, nvalid, c2);
    attn_kernel<<<dim3(1024), 512, 0, stream>>>(qpE, kpE, v, kidx, nvalid, wv, O_part, ml);
    combine_kernel<<<dim3(512), 128, 0, stream>>>(O_part, ml, out);
}

// Round 8
// 65.710 us; speedup vs baseline: 1.2770x; 1.1654x over previous
//
#include <hip/hip_runtime.h>
#include <hip/hip_bf16.h>

#define B_ 4
#define Q_ 256
#define K_ 1024
#define D_ 256
#define LOG2E 1.44269504f

__device__ __forceinline__ float fexp2(float x) {
    float r; asm("v_exp_f32 %0, %1" : "=v"(r) : "v"(x)); return r;
}
__device__ __forceinline__ float frcp(float x) {
    float r; asm("v_rcp_f32 %0, %1" : "=v"(r) : "v"(x)); return r;
}
__device__ __forceinline__ void gload_lds16(const void* g, void* l) {
    __builtin_amdgcn_global_load_lds((const __attribute__((address_space(1))) void*)g,
                                     (__attribute__((address_space(3))) void*)l, 16, 0, 0);
}

// Fused: blocks (x<80, y) do the two projections (output = exp2(c2 * A@W));
// blocks (80, y) do per-batch mask compaction.
__global__ __launch_bounds__(256) void prep_kernel(const float* __restrict__ q,
                                                   const float* __restrict__ k,
                                                   const float* __restrict__ Wq,
                                                   const float* __restrict__ Wk,
                                                   const int* __restrict__ mask,
                                                   float* __restrict__ qpE,
                                                   float* __restrict__ kpE,
                                                   ushort* __restrict__ kidx,
                                                   int* __restrict__ nvalid,
                                                   float scale) {
    const int t = threadIdx.x;
    if (blockIdx.x >= 80) {
        if (t >= 64) return;
        const int b = blockIdx.y, lane = t;
        const int* m = mask + b * K_;
        const int base = lane * 16;
        int cnt = 0;
#pragma unroll
        for (int i = 0; i < 16; ++i) cnt += (m[base + i] != 0);
        int inc = cnt;
#pragma unroll
        for (int d = 1; d < 64; d <<= 1) {
            int tt = __shfl_up(inc, d);
            if (lane >= d) inc += tt;
        }
        const int total = __shfl(inc, 63);
        int pos = inc - cnt;
        ushort* kb = kidx + b * K_;
        for (int i = 0; i < 16; ++i) {
            int kk = base + i;
            if (m[kk] != 0) kb[pos++] = (ushort)kk;
        }
        for (int j = total + lane; j < K_; j += 64) kb[j] = 0;
        if (lane == 0) nvalid[b] = total;
        return;
    }
    const float* A; const float* W; float* outp; int m0;
    if (blockIdx.x < 16) { A = q; W = Wq; outp = qpE; m0 = blockIdx.x * 64; }
    else                 { A = k; W = Wk; outp = kpE; m0 = (blockIdx.x - 16) * 64; }
    __shared__ float As[16][65];
    __shared__ float Ws[16][64];
    const int tx = t & 15, ty = t >> 4;
    const int n0 = blockIdx.y * 64;
    const int ar = t >> 2, ac = (t & 3) * 4;
    const int wr = t >> 4, wc = (t & 15) * 4;
    float c[4][4] = {};
    for (int kb = 0; kb < 256; kb += 16) {
        __syncthreads();
        float4 av = *(const float4*)(A + (size_t)(m0 + ar) * 256 + kb + ac);
        As[ac + 0][ar] = av.x; As[ac + 1][ar] = av.y;
        As[ac + 2][ar] = av.z; As[ac + 3][ar] = av.w;
        float4 wvv = *(const float4*)(W + (size_t)(kb + wr) * 256 + n0 + wc);
        wvv.x *= scale; wvv.y *= scale; wvv.z *= scale; wvv.w *= scale;
        *(float4*)(&Ws[wr][wc]) = wvv;
        __syncthreads();
#pragma unroll
        for (int kk = 0; kk < 16; ++kk) {
            float4 bv = *(const float4*)(&Ws[kk][tx * 4]);
#pragma unroll
            for (int i = 0; i < 4; ++i) {
                float a = As[kk][ty * 4 + i];
                c[i][0] = fmaf(a, bv.x, c[i][0]);
                c[i][1] = fmaf(a, bv.y, c[i][1]);
                c[i][2] = fmaf(a, bv.z, c[i][2]);
                c[i][3] = fmaf(a, bv.w, c[i][3]);
            }
        }
    }
#pragma unroll
    for (int i = 0; i < 4; ++i) {
        float4 o = make_float4(fexp2(c[i][0]), fexp2(c[i][1]),
                               fexp2(c[i][2]), fexp2(c[i][3]));
        *(float4*)(outp + (size_t)(m0 + ty * 4 + i) * 256 + n0 + tx * 4) = o;
    }
}

// Grid = 512 = B * 128 qpairs (full K per block). 1024 threads = 16 waves.
// Wave w owns e-chunk [w*16, w*16+16); lane = (kl = lane&31, eh = lane>>5),
// each lane handles 8 e's for 32 k's -> qp_A[2][8]+wv_r[8] = 24 live floats.
// sigmoid(2(qp+kp)) = 1/(A*B+1), A=exp2(c*qp) (regs), B=exp2(c*kp) (LDS dbuf).
// __launch_bounds__(1024,2): hipcc arg2 = blocks/CU -> 8 waves/SIMD -> VGPR<=64.
__global__ __launch_bounds__(1024, 2) void attn_kernel(const float* __restrict__ qpE,
                                                       const float* __restrict__ kpE,
                                                       const float* __restrict__ v,
                                                       const ushort* __restrict__ kidx_g,
                                                       const int* __restrict__ nvalid_g,
                                                       const float* __restrict__ wv,
                                                       float* __restrict__ out) {
    __shared__ float4 s_kp[2][32 * 65];   // 66,560 B : dbuf kp-exp tiles (stride 65 f4)
    __shared__ float  s_red[16 * 66];     //  4,224 B : cross-wave partials
    __shared__ float  s_sc[2][1024];      //  8,192 B : scores then unnormalized probs
    __shared__ ushort s_kidx[1024];       //  2,048 B : compacted k indices
    __shared__ float  s_inv[2];           //      8 B : 1/softmax-denominator

    const int tid  = threadIdx.x;
    const int lane = tid & 63;
    const int wave = tid >> 6;            // 0..15
    const int kl   = lane & 31;
    const int eh   = lane >> 5;

    int bid = blockIdx.x;
    bid = (bid & 7) * 64 + (bid >> 3);    // bijective XCD swizzle (512 % 8 == 0)
    const int b  = bid >> 7;
    const int qi = bid & 127;
    const int q0 = qi * 2;

    const int nv     = nvalid_g[b];
    const int ntiles = (nv + 31) >> 5;
    const int ntot   = ntiles << 5;

    s_kidx[tid] = (tid < nv) ? kidx_g[b * K_ + tid] : (ushort)0;

    // per-lane registers: A = exp2(c*qp) for 8 e's + wv chunk
    float qp_A[2][8], wv_r[8];
    {
        const int e0 = wave * 16 + eh * 8;
#pragma unroll
        for (int qq = 0; qq < 2; ++qq) {
            const float4* p = (const float4*)(qpE + ((size_t)(b * Q_ + q0 + qq) << 8) + e0);
#pragma unroll
            for (int i = 0; i < 2; ++i) {
                float4 x = p[i];
                qp_A[qq][i * 4 + 0] = x.x; qp_A[qq][i * 4 + 1] = x.y;
                qp_A[qq][i * 4 + 2] = x.z; qp_A[qq][i * 4 + 3] = x.w;
            }
        }
        const float4* pw = (const float4*)(wv + e0);
#pragma unroll
        for (int i = 0; i < 2; ++i) {
            float4 x = pw[i];
            wv_r[i * 4 + 0] = x.x; wv_r[i * 4 + 1] = x.y;
            wv_r[i * 4 + 2] = x.z; wv_r[i * 4 + 3] = x.w;
        }
    }
    __syncthreads();   // s_kidx ready

    const float4* srcb = (const float4*)(kpE + ((size_t)b * K_ << 8));

    // prologue: stage tile 0 into buf 0 (2 rows per wave)
    if (ntiles > 0) {
#pragma unroll
        for (int i = 0; i < 2; ++i) {
            const int row = wave * 2 + i;
            const int gr = s_kidx[row];
            gload_lds16(srcb + ((size_t)gr << 6) + lane, &s_kp[0][row * 65]);
        }
    }
    __syncthreads();   // tile 0 resident (vmcnt drained by barrier)

    for (int kt = 0; kt < ntiles; ++kt) {
        const int p = kt & 1;
        // ---- issue next tile's loads (hide under compute) ----
        if (kt + 1 < ntiles) {
            const int o = (kt + 1) * 32;
#pragma unroll
            for (int i = 0; i < 2; ++i) {
                const int row = wave * 2 + i;
                const int gr = s_kidx[o + row];
                gload_lds16(srcb + ((size_t)gr << 6) + lane, &s_kp[p ^ 1][row * 65]);
            }
        }
        // ---- sigmoid-weighted partial scores: fma, rcp, fma per (e,q) ----
        float a0 = 0.f, a1 = 0.f;
        const float4* krow = s_kp[p] + kl * 65 + wave * 4 + eh * 2;
#pragma unroll
        for (int t4 = 0; t4 < 2; ++t4) {
            float4 kv = krow[t4];
            float kc[4] = {kv.x, kv.y, kv.z, kv.w};
#pragma unroll
            for (int j = 0; j < 4; ++j) {
                const int e = t4 * 4 + j;
                const float w = wv_r[e];
                float r0 = frcp(fmaf(qp_A[0][e], kc[j], 1.0f));
                a0 = fmaf(w, r0, a0);
                float r1 = frcp(fmaf(qp_A[1][e], kc[j], 1.0f));
                a1 = fmaf(w, r1, a1);
            }
        }
        a0 += __shfl_xor(a0, 32);
        a1 += __shfl_xor(a1, 32);
        if (eh == 0) {
            s_red[wave * 66 + kl]      = a0;
            s_red[wave * 66 + 32 + kl] = a1;
        }
        __syncthreads();   // bar1: s_red ready; next tile's loads drained

        // ---- cross-wave reduce: thread (w=tid&15, slot=tid>>4) ----
        {
            const int w = tid & 15, sl = tid >> 4;      // sl = q*32 + kl
            float s = s_red[w * 66 + sl];
            s += __shfl_xor(s, 1);
            s += __shfl_xor(s, 2);
            s += __shfl_xor(s, 4);
            s += __shfl_xor(s, 8);
            if (w == 0) {
                const int idx = kt * 32 + (sl & 31);
                s_sc[sl >> 5][idx] = (idx < nv) ? (-2.0f * s) : -3.0e38f;
            }
        }
        __syncthreads();   // bar2: s_red reads done; safe to rewrite next iter
    }

    // ---- softmax stats: wave qq < 2 handles q = qq (unnormalized probs kept) ----
    if (wave < 2) {
        const int qq = wave;
        float mx = -3.0e38f;
        for (int j = lane; j < ntot; j += 64) mx = fmaxf(mx, s_sc[qq][j]);
#pragma unroll
        for (int off = 32; off > 0; off >>= 1) mx = fmaxf(mx, __shfl_xor(mx, off));
        float sum = 0.f;
        for (int j = lane; j < ntot; j += 64) {
            float e = fexp2((s_sc[qq][j] - mx) * LOG2E);
            s_sc[qq][j] = e;
            sum += e;
        }
#pragma unroll
        for (int off = 32; off > 0; off >>= 1) sum += __shfl_xor(sum, off);
        if (lane == 0) s_inv[qq] = frcp(sum);
    }
    __syncthreads();

    // ---- PV: thread -> (d-float4 = tid&63, k-chunk = tid>>6 of 16) ----
    {
        const int dl = tid & 63;
        const int kq = tid >> 6;
        const int chunk = ntiles * 2;                 // ntot / 16
        float4 o0 = {0, 0, 0, 0}, o1 = {0, 0, 0, 0};
        const float4* v4 = (const float4*)(v + ((size_t)b * K_ << 8));
        for (int k = kq * chunk; k < kq * chunk + chunk; ++k) {
            int vr = s_kidx[k];
            float4 vv = v4[((size_t)vr << 6) + dl];
            float p0 = s_sc[0][k], p1 = s_sc[1][k];
            o0.x = fmaf(p0, vv.x, o0.x); o0.y = fmaf(p0, vv.y, o0.y);
            o0.z = fmaf(p0, vv.z, o0.z); o0.w = fmaf(p0, vv.w, o0.w);
            o1.x = fmaf(p1, vv.x, o1.x); o1.y = fmaf(p1, vv.y, o1.y);
            o1.z = fmaf(p1, vv.z, o1.z); o1.w = fmaf(p1, vv.w, o1.w);
        }
        float4* s_pv = s_kp[0];                       // reuse (32 KB of 66.5)
        s_pv[(kq * 2 + 0) * 64 + dl] = o0;
        s_pv[(kq * 2 + 1) * 64 + dl] = o1;
        __syncthreads();
        if (tid < 128) {
            const int qq = tid >> 6, c = tid & 63;
            float4 s = {0, 0, 0, 0};
#pragma unroll
            for (int g = 0; g < 16; ++g) {
                float4 x = s_pv[(g * 2 + qq) * 64 + c];
                s.x += x.x; s.y += x.y; s.z += x.z; s.w += x.w;
            }
            const float inv = s_inv[qq];
            s.x *= inv; s.y *= inv; s.z *= inv; s.w *= inv;
            ((float4*)out)[((size_t)(b * Q_ + q0 + qq) << 6) + c] = s;
        }
    }
}

extern "C" void kernel_launch(void* const* d_in, const int* in_sizes, int n_in,
                              void* d_out, int out_size, void* d_ws, size_t ws_size,
                              hipStream_t stream) {
    const float* q    = (const float*)d_in[0];
    const float* k    = (const float*)d_in[1];
    const float* v    = (const float*)d_in[2];
    const int*   mask = (const int*)d_in[3];
    const float* Wq   = (const float*)d_in[4];
    const float* Wk   = (const float*)d_in[5];
    const float* wv   = (const float*)d_in[6];
    float* out = (float*)d_out;

    float* qpE    = (float*)d_ws;                        // 1 MB  (exp2 of c2*qp)
    float* kpE    = qpE + (size_t)B_ * Q_ * D_;          // 4 MB  (exp2 of c2*kp)
    ushort* kidx  = (ushort*)(kpE + (size_t)B_ * K_ * D_); // 8 KB
    int* nvalid   = (int*)(kidx + (size_t)B_ * K_);      // 16 B

    const float c2 = 2.885390082f;  // 2*log2(e)

    prep_kernel<<<dim3(81, 4), 256, 0, stream>>>(q, k, Wq, Wk, mask, qpE, kpE, kidx, nvalid, c2);
    attn_kernel<<<dim3(512), 1024, 0, stream>>>(qpE, kpE, v, kidx, nvalid, wv, out);
}